// Round 1
// baseline (1650.225 us; speedup 1.0000x reference)
//
#include <hip/hip_runtime.h>
#include <math.h>

// MoE: E=8 experts, top-2, D=512, H=2048, N=4096 tokens, fp32.
// Sparse (routed) evaluation: gate -> per-expert token lists -> fused
// 2-layer MLP per (expert, 16-token tile), atomicAdd combine into out.

#define N_TOK 4096
#define D_IN  512
#define H_DIM 2048
#define N_EXP 8
#define TM    16                 // tokens per expert tile
#define MAXT  (N_TOK / TM)       // 256 tiles max per expert
#define XS_STRIDE 520            // padded row stride for x tile (16B-aligned)
#define HS_STRIDE 68             // padded row stride for h chunk (16B-aligned)

// ---------------------------------------------------------------------------
// Gating: one wave (64 lanes) per token.
//   logits = x[n] @ Wg + bg  (lane l covers d = l*8 .. l*8+7, butterfly reduce)
//   softmax -> gates out; top-2 (strict > ascending scan == jax top_k tie rule)
//   atomic-append (token, gateweight) to per-expert lists in workspace.
// ---------------------------------------------------------------------------
__global__ __launch_bounds__(64) void moe_gate(
    const float* __restrict__ x, const float* __restrict__ Wg,
    const float* __restrict__ bg, float* __restrict__ gates,
    int* __restrict__ counts, int* __restrict__ lists, float* __restrict__ cwA)
{
    const int n = blockIdx.x;
    const int l = threadIdx.x;
    const float* xr  = x + (size_t)n * D_IN + l * 8;
    const float* wgr = Wg + (size_t)l * 8 * N_EXP;

    float xv[8];
    *(float4*)&xv[0] = *(const float4*)xr;
    *(float4*)&xv[4] = *(const float4*)(xr + 4);

    float acc[8] = {0.f, 0.f, 0.f, 0.f, 0.f, 0.f, 0.f, 0.f};
#pragma unroll
    for (int dd = 0; dd < 8; ++dd) {
        float4 wa = *(const float4*)(wgr + dd * N_EXP);
        float4 wb = *(const float4*)(wgr + dd * N_EXP + 4);
        acc[0] = fmaf(xv[dd], wa.x, acc[0]);
        acc[1] = fmaf(xv[dd], wa.y, acc[1]);
        acc[2] = fmaf(xv[dd], wa.z, acc[2]);
        acc[3] = fmaf(xv[dd], wa.w, acc[3]);
        acc[4] = fmaf(xv[dd], wb.x, acc[4]);
        acc[5] = fmaf(xv[dd], wb.y, acc[5]);
        acc[6] = fmaf(xv[dd], wb.z, acc[6]);
        acc[7] = fmaf(xv[dd], wb.w, acc[7]);
    }
    // 64-lane butterfly reduction (wave = 64 on CDNA)
#pragma unroll
    for (int off = 32; off >= 1; off >>= 1) {
#pragma unroll
        for (int e = 0; e < N_EXP; ++e)
            acc[e] += __shfl_xor(acc[e], off);
    }

    float g[8];
    float mx = -3.4e38f;
#pragma unroll
    for (int e = 0; e < N_EXP; ++e) { g[e] = acc[e] + bg[e]; mx = fmaxf(mx, g[e]); }
    float s = 0.f;
#pragma unroll
    for (int e = 0; e < N_EXP; ++e) { g[e] = expf(g[e] - mx); s += g[e]; }
    const float inv = 1.0f / s;
#pragma unroll
    for (int e = 0; e < N_EXP; ++e) g[e] *= inv;

    if (l == 0) {
        float* go = gates + (size_t)n * N_EXP;
        *(float4*)go       = make_float4(g[0], g[1], g[2], g[3]);
        *(float4*)(go + 4) = make_float4(g[4], g[5], g[6], g[7]);

        int e1 = 0; float g1 = g[0];
#pragma unroll
        for (int e = 1; e < N_EXP; ++e) if (g[e] > g1) { g1 = g[e]; e1 = e; }
        int e2 = -1; float g2 = -1.f;
#pragma unroll
        for (int e = 0; e < N_EXP; ++e) if (e != e1 && g[e] > g2) { g2 = g[e]; e2 = e; }

        int p1 = atomicAdd(&counts[e1], 1);
        lists[e1 * N_TOK + p1] = n;  cwA[e1 * N_TOK + p1] = g1;
        int p2 = atomicAdd(&counts[e2], 1);
        lists[e2 * N_TOK + p2] = n;  cwA[e2 * N_TOK + p2] = g2;
    }
}

// ---------------------------------------------------------------------------
// Fused expert MLP: block = 256 threads, one (expert, 16-token tile).
//   xs[16][512] staged in LDS once. Loop H in chunks of 64:
//     GEMM1: h[16][64] = relu(xs @ W1[:,chunk] + b1)  -> LDS
//     GEMM2: y[16][512] += h @ W2[chunk,:]            -> registers
//   Epilogue: atomicAdd (y + b2) * combine into out (exactly 2 adds/element).
//   All LDS reads in the GEMMs are wave-broadcast (conflict-free); all global
//   loads are 32/64-consecutive-dword coalesced.
// ---------------------------------------------------------------------------
__global__ __launch_bounds__(256, 4) void moe_expert(
    const float* __restrict__ x,  const float* __restrict__ W1,
    const float* __restrict__ b1, const float* __restrict__ W2,
    const float* __restrict__ b2, float* __restrict__ out,
    const int* __restrict__ counts, const int* __restrict__ lists,
    const float* __restrict__ cwA)
{
    const int e    = blockIdx.x & 7;
    const int tile = blockIdx.x >> 3;
    const int cnt  = counts[e];
    if (tile * TM >= cnt) return;

    __shared__ float xs[TM * XS_STRIDE];   // 33,280 B
    __shared__ float hs[TM * HS_STRIDE];   //  4,352 B
    __shared__ int   tokS[TM];
    __shared__ float cwS[TM];

    const int tid = threadIdx.x;
    if (tid < TM) {
        int gi = tile * TM + tid;
        bool v = gi < cnt;
        tokS[tid] = v ? lists[e * N_TOK + gi] : 0;
        cwS[tid]  = v ? cwA[e * N_TOK + gi]  : 0.f;   // cw=0 => contributes nothing
    }
    __syncthreads();

    // Stage x tile: 16 threads per row, 32 floats (8 x float4) each.
    {
        const int i = tid >> 4;         // row 0..15
        const int p = tid & 15;         // part 0..15
        const float* xr = x + (size_t)tokS[i] * D_IN + p * 32;
        float* xd = xs + i * XS_STRIDE + p * 32;
#pragma unroll
        for (int q = 0; q < 8; ++q)
            *(float4*)(xd + q * 4) = *(const float4*)(xr + q * 4);
    }
    __syncthreads();

    const float* W1e = W1 + (size_t)e * D_IN * H_DIM;   // [D][H] row-major
    const float* W2e = W2 + (size_t)e * H_DIM * D_IN;   // [H][D] row-major

    const int j   = tid & 31;   // gemm1 cols j, j+32 of the 64-chunk
    const int rg1 = tid >> 5;   // gemm1 rows rg1*2, rg1*2+1
    const int cg  = tid & 63;   // gemm2 cols cg + 64*m
    const int rg2 = tid >> 6;   // gemm2 rows rg2*4 .. +3

    float acc[4][8];
#pragma unroll
    for (int i = 0; i < 4; ++i)
#pragma unroll
        for (int m = 0; m < 8; ++m) acc[i][m] = 0.f;

    for (int hc = 0; hc < H_DIM / 64; ++hc) {
        // ---- GEMM1: 16x64 chunk of h ----
        float a1[2][2] = {{0.f, 0.f}, {0.f, 0.f}};
        const float* w1p = W1e + hc * 64 + j;
        for (int d = 0; d < D_IN; d += 4) {
            float xv[2][4];
            *(float4*)xv[0] = *(const float4*)(xs + (rg1 * 2 + 0) * XS_STRIDE + d);
            *(float4*)xv[1] = *(const float4*)(xs + (rg1 * 2 + 1) * XS_STRIDE + d);
#pragma unroll
            for (int dd = 0; dd < 4; ++dd) {
                float wa = w1p[(size_t)(d + dd) * H_DIM];
                float wb = w1p[(size_t)(d + dd) * H_DIM + 32];
                a1[0][0] = fmaf(xv[0][dd], wa, a1[0][0]);
                a1[0][1] = fmaf(xv[0][dd], wb, a1[0][1]);
                a1[1][0] = fmaf(xv[1][dd], wa, a1[1][0]);
                a1[1][1] = fmaf(xv[1][dd], wb, a1[1][1]);
            }
        }
        float b1a = b1[e * H_DIM + hc * 64 + j];
        float b1b = b1[e * H_DIM + hc * 64 + j + 32];

        __syncthreads();   // prev chunk's GEMM2 done reading hs
        hs[(rg1 * 2 + 0) * HS_STRIDE + j]      = fmaxf(a1[0][0] + b1a, 0.f);
        hs[(rg1 * 2 + 0) * HS_STRIDE + j + 32] = fmaxf(a1[0][1] + b1b, 0.f);
        hs[(rg1 * 2 + 1) * HS_STRIDE + j]      = fmaxf(a1[1][0] + b1a, 0.f);
        hs[(rg1 * 2 + 1) * HS_STRIDE + j + 32] = fmaxf(a1[1][1] + b1b, 0.f);
        __syncthreads();

        // ---- GEMM2: y[16][512] += h_chunk @ W2[chunk, :] ----
        const float* w2p = W2e + (size_t)(hc * 64) * D_IN + cg;
        for (int k = 0; k < 64; k += 4) {
            float hv[4][4];
#pragma unroll
            for (int i = 0; i < 4; ++i)
                *(float4*)hv[i] = *(const float4*)(hs + (rg2 * 4 + i) * HS_STRIDE + k);
#pragma unroll
            for (int kk = 0; kk < 4; ++kk) {
                float w2r[8];
#pragma unroll
                for (int m = 0; m < 8; ++m)
                    w2r[m] = w2p[(size_t)(k + kk) * D_IN + 64 * m];
#pragma unroll
                for (int i = 0; i < 4; ++i)
#pragma unroll
                    for (int m = 0; m < 8; ++m)
                        acc[i][m] = fmaf(hv[i][kk], w2r[m], acc[i][m]);
            }
        }
        __syncthreads();   // done reading hs before next chunk overwrites
    }

    // ---- Epilogue: out[tok] += (y + b2) * combine ----
    float b2v[8];
#pragma unroll
    for (int m = 0; m < 8; ++m) b2v[m] = b2[e * D_IN + cg + 64 * m];
#pragma unroll
    for (int i = 0; i < 4; ++i) {
        const int r = rg2 * 4 + i;
        const float cw = cwS[r];
        float* op = out + (size_t)tokS[r] * D_IN + cg;
#pragma unroll
        for (int m = 0; m < 8; ++m)
            atomicAdd(op + 64 * m, (acc[i][m] + b2v[m]) * cw);
    }
}

// ---------------------------------------------------------------------------
extern "C" void kernel_launch(void* const* d_in, const int* in_sizes, int n_in,
                              void* d_out, int out_size, void* d_ws, size_t ws_size,
                              hipStream_t stream) {
    const float* x  = (const float*)d_in[0];
    const float* Wg = (const float*)d_in[1];
    const float* bg = (const float*)d_in[2];
    const float* W1 = (const float*)d_in[3];
    const float* b1 = (const float*)d_in[4];
    const float* W2 = (const float*)d_in[5];
    const float* b2 = (const float*)d_in[6];

    float* out   = (float*)d_out;
    float* gates = out + (size_t)N_TOK * D_IN;   // second output, concatenated

    // workspace: [counts 8*int | pad to 64B | lists 8*4096*int | cw 8*4096*float]
    int*   counts = (int*)d_ws;
    int*   lists  = (int*)((char*)d_ws + 64);
    float* cwA    = (float*)((char*)d_ws + 64 + (size_t)N_EXP * N_TOK * sizeof(int));

    hipMemsetAsync(d_out, 0, (size_t)N_TOK * D_IN * sizeof(float), stream);
    hipMemsetAsync(d_ws, 0, 64, stream);  // zero the expert counters

    moe_gate<<<N_TOK, 64, 0, stream>>>(x, Wg, bg, gates, counts, lists, cwA);
    moe_expert<<<N_EXP * MAXT, 256, 0, stream>>>(x, W1, b1, W2, b2, out,
                                                 counts, lists, cwA);
}

// Round 2
// 644.059 us; speedup vs baseline: 2.5622x; 2.5622x over previous
//
#include <hip/hip_runtime.h>
#include <math.h>
#include <stdint.h>

// MoE: E=8, top-2, D=512, H=2048, N=4096, fp32 in/out.
// Round 2: split-bf16 3-pass MFMA expert kernel.
//   prep: x -> (xhi,xlo) bf16; W1 -> W1T[e][H][D] hi/lo; W2 -> W2T[e][D][H] hi/lo
//   expert: per (expert, 32-token tile, 256-h slice): GEMM1 via mfma_16x16x32_bf16
//           (frags loaded straight from global, 16B/lane), h -> LDS (C-layout ->
//           A-layout transform), GEMM2 via mfma, atomicAdd combine.
// Fallback: if ws_size too small, round-1 fp32 kernel (known-passing).

#define N_TOK 4096
#define D_IN  512
#define H_DIM 2048
#define N_EXP 8

typedef float  f32x4  __attribute__((ext_vector_type(4)));
typedef short  short8 __attribute__((ext_vector_type(8)));
typedef unsigned short u16;

__device__ __forceinline__ u16 bf16_rne(float f) {
    uint32_t u = __float_as_uint(f);
    return (u16)((u + 0x7fffu + ((u >> 16) & 1u)) >> 16);
}
__device__ __forceinline__ float bf16_tof(u16 h) {
    return __uint_as_float(((uint32_t)h) << 16);
}

// ---------------------------------------------------------------------------
// Gating: one wave per token (unchanged from round 1 — verified correct).
// ---------------------------------------------------------------------------
__global__ __launch_bounds__(64) void moe_gate(
    const float* __restrict__ x, const float* __restrict__ Wg,
    const float* __restrict__ bg, float* __restrict__ gates,
    int* __restrict__ counts, int* __restrict__ lists, float* __restrict__ cwA)
{
    const int n = blockIdx.x;
    const int l = threadIdx.x;
    const float* xr  = x + (size_t)n * D_IN + l * 8;
    const float* wgr = Wg + (size_t)l * 8 * N_EXP;

    float xv[8];
    *(float4*)&xv[0] = *(const float4*)xr;
    *(float4*)&xv[4] = *(const float4*)(xr + 4);

    float acc[8] = {0.f, 0.f, 0.f, 0.f, 0.f, 0.f, 0.f, 0.f};
#pragma unroll
    for (int dd = 0; dd < 8; ++dd) {
        float4 wa = *(const float4*)(wgr + dd * N_EXP);
        float4 wb = *(const float4*)(wgr + dd * N_EXP + 4);
        acc[0] = fmaf(xv[dd], wa.x, acc[0]);
        acc[1] = fmaf(xv[dd], wa.y, acc[1]);
        acc[2] = fmaf(xv[dd], wa.z, acc[2]);
        acc[3] = fmaf(xv[dd], wa.w, acc[3]);
        acc[4] = fmaf(xv[dd], wb.x, acc[4]);
        acc[5] = fmaf(xv[dd], wb.y, acc[5]);
        acc[6] = fmaf(xv[dd], wb.z, acc[6]);
        acc[7] = fmaf(xv[dd], wb.w, acc[7]);
    }
#pragma unroll
    for (int off = 32; off >= 1; off >>= 1) {
#pragma unroll
        for (int e = 0; e < N_EXP; ++e)
            acc[e] += __shfl_xor(acc[e], off);
    }

    float g[8];
    float mx = -3.4e38f;
#pragma unroll
    for (int e = 0; e < N_EXP; ++e) { g[e] = acc[e] + bg[e]; mx = fmaxf(mx, g[e]); }
    float s = 0.f;
#pragma unroll
    for (int e = 0; e < N_EXP; ++e) { g[e] = expf(g[e] - mx); s += g[e]; }
    const float inv = 1.0f / s;
#pragma unroll
    for (int e = 0; e < N_EXP; ++e) g[e] *= inv;

    if (l == 0) {
        float* go = gates + (size_t)n * N_EXP;
        *(float4*)go       = make_float4(g[0], g[1], g[2], g[3]);
        *(float4*)(go + 4) = make_float4(g[4], g[5], g[6], g[7]);

        int e1 = 0; float g1 = g[0];
#pragma unroll
        for (int e = 1; e < N_EXP; ++e) if (g[e] > g1) { g1 = g[e]; e1 = e; }
        int e2 = -1; float g2 = -1.f;
#pragma unroll
        for (int e = 0; e < N_EXP; ++e) if (e != e1 && g[e] > g2) { g2 = g[e]; e2 = e; }

        int p1 = atomicAdd(&counts[e1], 1);
        lists[e1 * N_TOK + p1] = n;  cwA[e1 * N_TOK + p1] = g1;
        int p2 = atomicAdd(&counts[e2], 1);
        lists[e2 * N_TOK + p2] = n;  cwA[e2 * N_TOK + p2] = g2;
    }
}

// ---------------------------------------------------------------------------
// Prep: x (fp32) -> xhi/xlo bf16. One thread per 4 elements.
// ---------------------------------------------------------------------------
__global__ __launch_bounds__(256) void conv_x(
    const float* __restrict__ x, u16* __restrict__ xhi, u16* __restrict__ xlo)
{
    const int gid = blockIdx.x * 256 + threadIdx.x;   // < N_TOK*D_IN/4
    float4 v = ((const float4*)x)[gid];
    float f[4] = {v.x, v.y, v.z, v.w};
    u16 h[4], l[4];
#pragma unroll
    for (int i = 0; i < 4; ++i) {
        h[i] = bf16_rne(f[i]);
        l[i] = bf16_rne(f[i] - bf16_tof(h[i]));
    }
    ((ushort4*)xhi)[gid] = make_ushort4(h[0], h[1], h[2], h[3]);
    ((ushort4*)xlo)[gid] = make_ushort4(l[0], l[1], l[2], l[3]);
}

// ---------------------------------------------------------------------------
// Prep: tiled transpose + hi/lo split.  in[e][R][C] -> out[e][C][R] (bf16 x2).
// grid = (C/64, R/64, E), 256 threads. Coalesced read and write via LDS tile.
// ---------------------------------------------------------------------------
__global__ __launch_bounds__(256) void conv_w_t(
    const float* __restrict__ in, u16* __restrict__ ohi, u16* __restrict__ olo,
    int R, int C)
{
    __shared__ u16 th[64][65];
    __shared__ u16 tl[64][65];
    const int e  = blockIdx.z;
    const size_t base = (size_t)e * R * C;
    const int c0 = blockIdx.x * 64, r0 = blockIdx.y * 64;
    const int c  = threadIdx.x & 63, rq = threadIdx.x >> 6;

#pragma unroll
    for (int i = 0; i < 16; ++i) {
        int r = rq * 16 + i;
        float f = in[base + (size_t)(r0 + r) * C + c0 + c];
        u16 h = bf16_rne(f);
        th[r][c] = h;
        tl[r][c] = bf16_rne(f - bf16_tof(h));
    }
    __syncthreads();
#pragma unroll
    for (int i = 0; i < 16; ++i) {
        int rw = rq * 16 + i;                       // output row within tile (orig col)
        size_t o = base + (size_t)(c0 + rw) * R + r0 + c;
        ohi[o] = th[c][rw];
        olo[o] = tl[c][rw];
    }
}

// ---------------------------------------------------------------------------
// MFMA expert kernel.
//   TM=32 tokens/tile, HS=256 h-cols/slice, 4 waves (256 thr).
//   blockIdx swizzle: b = s + 8*(t + 128*e)  => XCD (b%8) pins the h-slice,
//   consecutive blocks on an XCD walk tiles of one (e,s) -> 1MB L2 working set.
//   GEMM1: per wave 2 m-tiles x 4 n-tiles; frags direct from global bf16.
//   h -> LDS (hi/lo, padded stride 264 => 2-way-bank-free b128 reads).
//   GEMM2: per wave 2 m-tiles x 8 n-tiles over K=256 slice.
// ---------------------------------------------------------------------------
#define TM    32
#define HS    256
#define HPAD  264
#define MAXT2 128

__global__ __launch_bounds__(256, 2) void moe_expert_mfma(
    const u16* __restrict__ xhi, const u16* __restrict__ xlo,
    const u16* __restrict__ w1thi, const u16* __restrict__ w1tlo,
    const u16* __restrict__ w2thi, const u16* __restrict__ w2tlo,
    const float* __restrict__ b1, const float* __restrict__ b2,
    float* __restrict__ out,
    const int* __restrict__ counts, const int* __restrict__ lists,
    const float* __restrict__ cwA)
{
    const int b  = blockIdx.x;
    const int s  = b & 7;                 // h-slice (XCD-pinned)
    const int rb = b >> 3;
    const int t  = rb & (MAXT2 - 1);      // token tile
    const int e  = rb >> 7;               // expert
    const int cnt = counts[e];
    if (t * TM >= cnt) return;

    __shared__ __align__(16) u16 hHi[TM * HPAD];
    __shared__ __align__(16) u16 hLo[TM * HPAD];
    __shared__ int   tokS[TM];
    __shared__ float cwS[TM];

    const int tid  = threadIdx.x;
    const int w    = tid >> 6;
    const int lane = tid & 63;
    const int quad = lane >> 4;
    const int l16  = lane & 15;

    if (tid < TM) {
        int gi = t * TM + tid;
        bool v = gi < cnt;
        tokS[tid] = v ? lists[e * N_TOK + gi] : 0;
        cwS[tid]  = v ? cwA[e * N_TOK + gi] : 0.f;   // cw=0 kills pad rows
    }
    __syncthreads();

    // ---------------- GEMM1: h[32][256-slice] = x @ W1 ----------------
    const u16* aHp0 = xhi + (size_t)tokS[l16]      * D_IN + quad * 8;
    const u16* aLp0 = xlo + (size_t)tokS[l16]      * D_IN + quad * 8;
    const u16* aHp1 = xhi + (size_t)tokS[16 + l16] * D_IN + quad * 8;
    const u16* aLp1 = xlo + (size_t)tokS[16 + l16] * D_IN + quad * 8;

    const size_t wb1 = (size_t)e * H_DIM * D_IN;
    const int hcb = s * HS + w * 64 + l16;           // global h col base (+ nt*16)
    const u16* bHp[4]; const u16* bLp[4];
#pragma unroll
    for (int nt = 0; nt < 4; ++nt) {
        size_t o = wb1 + (size_t)(hcb + nt * 16) * D_IN + quad * 8;
        bHp[nt] = w1thi + o;
        bLp[nt] = w1tlo + o;
    }

    f32x4 acc1[2][4];
#pragma unroll
    for (int i = 0; i < 2; ++i)
#pragma unroll
        for (int j = 0; j < 4; ++j) acc1[i][j] = (f32x4){0.f, 0.f, 0.f, 0.f};

#pragma unroll 2
    for (int kk = 0; kk < D_IN / 32; ++kk) {
        const int ko = kk * 32;
        short8 a0h = *(const short8*)(aHp0 + ko);
        short8 a0l = *(const short8*)(aLp0 + ko);
        short8 a1h = *(const short8*)(aHp1 + ko);
        short8 a1l = *(const short8*)(aLp1 + ko);
#pragma unroll
        for (int nt = 0; nt < 4; ++nt) {
            short8 bh = *(const short8*)(bHp[nt] + ko);
            short8 bl = *(const short8*)(bLp[nt] + ko);
            acc1[0][nt] = __builtin_amdgcn_mfma_f32_16x16x32_bf16(a0h, bh, acc1[0][nt], 0, 0, 0);
            acc1[1][nt] = __builtin_amdgcn_mfma_f32_16x16x32_bf16(a1h, bh, acc1[1][nt], 0, 0, 0);
            acc1[0][nt] = __builtin_amdgcn_mfma_f32_16x16x32_bf16(a0l, bh, acc1[0][nt], 0, 0, 0);
            acc1[1][nt] = __builtin_amdgcn_mfma_f32_16x16x32_bf16(a1l, bh, acc1[1][nt], 0, 0, 0);
            acc1[0][nt] = __builtin_amdgcn_mfma_f32_16x16x32_bf16(a0h, bl, acc1[0][nt], 0, 0, 0);
            acc1[1][nt] = __builtin_amdgcn_mfma_f32_16x16x32_bf16(a1h, bl, acc1[1][nt], 0, 0, 0);
        }
    }

    // Epilogue 1: bias + relu, hi/lo split, C-layout -> A-layout via LDS.
#pragma unroll
    for (int nt = 0; nt < 4; ++nt) {
        const int colL = w * 64 + nt * 16 + l16;     // 0..255 slice-local
        const float bias = b1[e * H_DIM + s * HS + colL];
#pragma unroll
        for (int mt = 0; mt < 2; ++mt) {
#pragma unroll
            for (int r = 0; r < 4; ++r) {
                int row = mt * 16 + quad * 4 + r;    // token-local
                float v = fmaxf(acc1[mt][nt][r] + bias, 0.f);
                u16 h = bf16_rne(v);
                hHi[row * HPAD + colL] = h;
                hLo[row * HPAD + colL] = bf16_rne(v - bf16_tof(h));
            }
        }
    }
    __syncthreads();

    // ---------------- GEMM2: y[32][512] = h @ W2-slice ----------------
    const size_t wb2 = (size_t)e * D_IN * H_DIM;
    const int dcb = w * 128 + l16;                   // d col base (+ nt*16)
    const u16* b2Hp[8]; const u16* b2Lp[8];
#pragma unroll
    for (int nt = 0; nt < 8; ++nt) {
        size_t o = wb2 + (size_t)(dcb + nt * 16) * H_DIM + s * HS + quad * 8;
        b2Hp[nt] = w2thi + o;
        b2Lp[nt] = w2tlo + o;
    }
    const int arow0 = l16 * HPAD;
    const int arow1 = (16 + l16) * HPAD;

    f32x4 acc2[2][8];
#pragma unroll
    for (int i = 0; i < 2; ++i)
#pragma unroll
        for (int j = 0; j < 8; ++j) acc2[i][j] = (f32x4){0.f, 0.f, 0.f, 0.f};

    for (int kk = 0; kk < HS / 32; ++kk) {
        const int ko = kk * 32 + quad * 8;
        short8 a0h = *(const short8*)&hHi[arow0 + ko];
        short8 a0l = *(const short8*)&hLo[arow0 + ko];
        short8 a1h = *(const short8*)&hHi[arow1 + ko];
        short8 a1l = *(const short8*)&hLo[arow1 + ko];
#pragma unroll
        for (int nt = 0; nt < 8; ++nt) {
            short8 bh = *(const short8*)(b2Hp[nt] + kk * 32);
            short8 bl = *(const short8*)(b2Lp[nt] + kk * 32);
            acc2[0][nt] = __builtin_amdgcn_mfma_f32_16x16x32_bf16(a0h, bh, acc2[0][nt], 0, 0, 0);
            acc2[1][nt] = __builtin_amdgcn_mfma_f32_16x16x32_bf16(a1h, bh, acc2[1][nt], 0, 0, 0);
            acc2[0][nt] = __builtin_amdgcn_mfma_f32_16x16x32_bf16(a0l, bh, acc2[0][nt], 0, 0, 0);
            acc2[1][nt] = __builtin_amdgcn_mfma_f32_16x16x32_bf16(a1l, bh, acc2[1][nt], 0, 0, 0);
            acc2[0][nt] = __builtin_amdgcn_mfma_f32_16x16x32_bf16(a0h, bl, acc2[0][nt], 0, 0, 0);
            acc2[1][nt] = __builtin_amdgcn_mfma_f32_16x16x32_bf16(a1h, bl, acc2[1][nt], 0, 0, 0);
        }
    }

    // Epilogue 2: bias, combine weight, atomicAdd (2 contributions/elem total).
#pragma unroll
    for (int nt = 0; nt < 8; ++nt) {
        const int dcol = w * 128 + nt * 16 + l16;
        const float bias = b2[e * D_IN + dcol];
#pragma unroll
        for (int mt = 0; mt < 2; ++mt) {
#pragma unroll
            for (int r = 0; r < 4; ++r) {
                int m = mt * 16 + quad * 4 + r;
                float v = (acc2[mt][nt][r] + bias) * cwS[m];
                atomicAdd(out + (size_t)tokS[m] * D_IN + dcol, v);
            }
        }
    }
}

// ---------------------------------------------------------------------------
// Fallback fp32 expert kernel (round 1, known-passing) — used if ws too small.
// ---------------------------------------------------------------------------
__global__ __launch_bounds__(256, 4) void moe_expert_fp32(
    const float* __restrict__ x,  const float* __restrict__ W1,
    const float* __restrict__ b1, const float* __restrict__ W2,
    const float* __restrict__ b2, float* __restrict__ out,
    const int* __restrict__ counts, const int* __restrict__ lists,
    const float* __restrict__ cwA)
{
    const int e    = blockIdx.x & 7;
    const int tile = blockIdx.x >> 3;
    const int cnt  = counts[e];
    if (tile * 16 >= cnt) return;

    __shared__ float xs[16 * 520];
    __shared__ float hs[16 * 68];
    __shared__ int   tokS[16];
    __shared__ float cwS[16];

    const int tid = threadIdx.x;
    if (tid < 16) {
        int gi = tile * 16 + tid;
        bool v = gi < cnt;
        tokS[tid] = v ? lists[e * N_TOK + gi] : 0;
        cwS[tid]  = v ? cwA[e * N_TOK + gi]  : 0.f;
    }
    __syncthreads();
    {
        const int i = tid >> 4, p = tid & 15;
        const float* xr = x + (size_t)tokS[i] * D_IN + p * 32;
        float* xd = xs + i * 520 + p * 32;
#pragma unroll
        for (int q = 0; q < 8; ++q)
            *(float4*)(xd + q * 4) = *(const float4*)(xr + q * 4);
    }
    __syncthreads();

    const float* W1e = W1 + (size_t)e * D_IN * H_DIM;
    const float* W2e = W2 + (size_t)e * H_DIM * D_IN;
    const int j = tid & 31, rg1 = tid >> 5, cg = tid & 63, rg2 = tid >> 6;

    float acc[4][8];
#pragma unroll
    for (int i = 0; i < 4; ++i)
#pragma unroll
        for (int m = 0; m < 8; ++m) acc[i][m] = 0.f;

    for (int hc = 0; hc < H_DIM / 64; ++hc) {
        float a1[2][2] = {{0.f, 0.f}, {0.f, 0.f}};
        const float* w1p = W1e + hc * 64 + j;
        for (int d = 0; d < D_IN; d += 4) {
            float xv[2][4];
            *(float4*)xv[0] = *(const float4*)(xs + (rg1 * 2 + 0) * 520 + d);
            *(float4*)xv[1] = *(const float4*)(xs + (rg1 * 2 + 1) * 520 + d);
#pragma unroll
            for (int dd = 0; dd < 4; ++dd) {
                float wa = w1p[(size_t)(d + dd) * H_DIM];
                float wb = w1p[(size_t)(d + dd) * H_DIM + 32];
                a1[0][0] = fmaf(xv[0][dd], wa, a1[0][0]);
                a1[0][1] = fmaf(xv[0][dd], wb, a1[0][1]);
                a1[1][0] = fmaf(xv[1][dd], wa, a1[1][0]);
                a1[1][1] = fmaf(xv[1][dd], wb, a1[1][1]);
            }
        }
        float b1a = b1[e * H_DIM + hc * 64 + j];
        float b1b = b1[e * H_DIM + hc * 64 + j + 32];
        __syncthreads();
        hs[(rg1 * 2 + 0) * 68 + j]      = fmaxf(a1[0][0] + b1a, 0.f);
        hs[(rg1 * 2 + 0) * 68 + j + 32] = fmaxf(a1[0][1] + b1b, 0.f);
        hs[(rg1 * 2 + 1) * 68 + j]      = fmaxf(a1[1][0] + b1a, 0.f);
        hs[(rg1 * 2 + 1) * 68 + j + 32] = fmaxf(a1[1][1] + b1b, 0.f);
        __syncthreads();
        const float* w2p = W2e + (size_t)(hc * 64) * D_IN + cg;
        for (int k = 0; k < 64; k += 4) {
            float hv[4][4];
#pragma unroll
            for (int i = 0; i < 4; ++i)
                *(float4*)hv[i] = *(const float4*)(hs + (rg2 * 4 + i) * 68 + k);
#pragma unroll
            for (int kk = 0; kk < 4; ++kk) {
                float w2r[8];
#pragma unroll
                for (int m = 0; m < 8; ++m)
                    w2r[m] = w2p[(size_t)(k + kk) * D_IN + 64 * m];
#pragma unroll
                for (int i = 0; i < 4; ++i)
#pragma unroll
                    for (int m = 0; m < 8; ++m)
                        acc[i][m] = fmaf(hv[i][kk], w2r[m], acc[i][m]);
            }
        }
        __syncthreads();
    }
    float b2v[8];
#pragma unroll
    for (int m = 0; m < 8; ++m) b2v[m] = b2[e * D_IN + cg + 64 * m];
#pragma unroll
    for (int i = 0; i < 4; ++i) {
        const int r = rg2 * 4 + i;
        const float cw = cwS[r];
        float* op = out + (size_t)tokS[r] * D_IN + cg;
#pragma unroll
        for (int m = 0; m < 8; ++m)
            atomicAdd(op + 64 * m, (acc[i][m] + b2v[m]) * cw);
    }
}

// ---------------------------------------------------------------------------
extern "C" void kernel_launch(void* const* d_in, const int* in_sizes, int n_in,
                              void* d_out, int out_size, void* d_ws, size_t ws_size,
                              hipStream_t stream) {
    const float* x  = (const float*)d_in[0];
    const float* Wg = (const float*)d_in[1];
    const float* bg = (const float*)d_in[2];
    const float* W1 = (const float*)d_in[3];
    const float* b1 = (const float*)d_in[4];
    const float* W2 = (const float*)d_in[5];
    const float* b2 = (const float*)d_in[6];

    float* out   = (float*)d_out;
    float* gates = out + (size_t)N_TOK * D_IN;

    // workspace layout (all offsets 16B-aligned)
    const size_t o_lists = 1024;
    const size_t o_cw    = o_lists + (size_t)N_EXP * N_TOK * 4;      //   132,096
    const size_t o_xhi   = o_cw + (size_t)N_EXP * N_TOK * 4;         //   263,168
    const size_t o_xlo   = o_xhi + (size_t)N_TOK * D_IN * 2;
    const size_t o_w1h   = o_xlo + (size_t)N_TOK * D_IN * 2;
    const size_t o_w1l   = o_w1h + (size_t)N_EXP * D_IN * H_DIM * 2;
    const size_t o_w2h   = o_w1l + (size_t)N_EXP * D_IN * H_DIM * 2;
    const size_t o_w2l   = o_w2h + (size_t)N_EXP * D_IN * H_DIM * 2;
    const size_t NEEDED  = o_w2l + (size_t)N_EXP * D_IN * H_DIM * 2; // ~75.8 MB

    int*   counts = (int*)d_ws;
    int*   lists  = (int*)((char*)d_ws + o_lists);
    float* cwA    = (float*)((char*)d_ws + o_cw);

    hipMemsetAsync(d_out, 0, (size_t)N_TOK * D_IN * sizeof(float), stream);
    hipMemsetAsync(d_ws, 0, 64, stream);   // expert counters

    moe_gate<<<N_TOK, 64, 0, stream>>>(x, Wg, bg, gates, counts, lists, cwA);

    if (ws_size >= NEEDED) {
        u16* xhi = (u16*)((char*)d_ws + o_xhi);
        u16* xlo = (u16*)((char*)d_ws + o_xlo);
        u16* w1h = (u16*)((char*)d_ws + o_w1h);
        u16* w1l = (u16*)((char*)d_ws + o_w1l);
        u16* w2h = (u16*)((char*)d_ws + o_w2h);
        u16* w2l = (u16*)((char*)d_ws + o_w2l);

        conv_x<<<(N_TOK * D_IN / 4) / 256, 256, 0, stream>>>(x, xhi, xlo);
        // W1[e][D][H] -> W1T[e][H][D]
        conv_w_t<<<dim3(H_DIM / 64, D_IN / 64, N_EXP), 256, 0, stream>>>(
            W1, w1h, w1l, D_IN, H_DIM);
        // W2[e][H][D] -> W2T[e][D][H]
        conv_w_t<<<dim3(D_IN / 64, H_DIM / 64, N_EXP), 256, 0, stream>>>(
            W2, w2h, w2l, H_DIM, D_IN);

        moe_expert_mfma<<<N_EXP * MAXT2 * 8, 256, 0, stream>>>(
            xhi, xlo, w1h, w1l, w2h, w2l, b1, b2, out, counts, lists, cwA);
    } else {
        moe_expert_fp32<<<N_EXP * 256, 256, 0, stream>>>(
            x, W1, b1, W2, b2, out, counts, lists, cwA);
    }
}